// Round 6
// baseline (158.802 us; speedup 1.0000x reference)
//
#include <hip/hip_runtime.h>
#include <cstdint>

// B=4, S=512, D=512, H=8, TM=20, DH=64
// out layout: out[1048576] | attn[8388608] | reg[1] | T_i[2048]  (all float)

typedef __attribute__((ext_vector_type(8))) _Float16 f16x8;
typedef __attribute__((ext_vector_type(4))) float f32x4;

__device__ __forceinline__ float sep_mad(float a, float b, float c) {
    // separate mul+add rounding (matches numpy), blocks FMA contraction:
    // spike threshold is discontinuous.
    float t = a * b;
    asm volatile("" : "+v"(t));
    return t + c;
}

union HU4 { _Float16 h[4]; ushort4 u; };
union HU8 { _Float16 h[8]; uint4 u; };

// ---------------- Kernel 0: fp32 -> fp16 convert (x, Wq|Wk|Wv, Wo) ----------------
__global__ __launch_bounds__(256) void k_convert(
    const float* __restrict__ x,
    const float* __restrict__ Wq, const float* __restrict__ Wk,
    const float* __restrict__ Wv, const float* __restrict__ Wo,
    _Float16* __restrict__ xh, _Float16* __restrict__ Wh, _Float16* __restrict__ Woh)
{
    const int t = blockIdx.x * 256 + threadIdx.x;   // one float4 per thread
    float4 v;
    HU4 hi;
    if (t < 262144) {
        v = ((const float4*)x)[t];
        hi.h[0] = (_Float16)v.x; hi.h[1] = (_Float16)v.y;
        hi.h[2] = (_Float16)v.z; hi.h[3] = (_Float16)v.w;
        ((ushort4*)xh)[t] = hi.u;
    } else {
        const int t2 = t - 262144;
        const int sel = t2 >> 16;          // 0..3 -> Wq, Wk, Wv, Wo
        const int o = t2 & 65535;
        const float* src = (sel == 0) ? Wq : ((sel == 1) ? Wk : ((sel == 2) ? Wv : Wo));
        v = ((const float4*)src)[o];
        hi.h[0] = (_Float16)v.x; hi.h[1] = (_Float16)v.y;
        hi.h[2] = (_Float16)v.z; hi.h[3] = (_Float16)v.w;
        if (sel < 3) ((ushort4*)(Wh + sel * 262144))[o] = hi.u;
        else         ((ushort4*)Woh)[o] = hi.u;
    }
}

// ---------------- Kernel 1: gate MLPs -> T_i  (1024 thr, 8 tokens, 1 dot/thread) ----------------
// 16 waves/block = 4 waves/SIMD at 1 block/CU: TLP hides weight-load latency.
__global__ __launch_bounds__(1024) void k_gates(
    const float* __restrict__ x,
    const float* __restrict__ gw1, const float* __restrict__ gb1,
    const float* __restrict__ gw2, const float* __restrict__ gb2,
    const float* __restrict__ gw3, const float* __restrict__ gb3,
    const float* __restrict__ cw1, const float* __restrict__ cb1,
    const float* __restrict__ cw2, const float* __restrict__ cb2,
    int* __restrict__ Ti, float* __restrict__ ti_out)
{
    __shared__ float xs[8][516];
    __shared__ float h1s[8][100];
    __shared__ float h2s[8][36];
    const int tok0 = blockIdx.x * 8;
    const int tid = threadIdx.x;

    // stage x tile: 8*128 float4 = 1024, one per thread
    {
        const int tok = tid >> 7, c4 = tid & 127;
        *(float4*)&xs[tok][c4 * 4] = ((const float4*)(x + (tok0 + tok) * 512))[c4];
    }
    __syncthreads();

    // layer 1: thread (tg = token 0..7, o = output 0..127; 96 real outputs)
    {
        const int o = tid & 127;
        const int tg = tid >> 7;
        const int oc = (o < 96) ? o : 95;
        const float4* wrow = (const float4*)((oc < 64) ? (gw1 + oc * 512) : (cw1 + (oc - 64) * 512));
        float acc = (oc < 64) ? gb1[oc] : cb1[oc - 64];
        for (int k4 = 0; k4 < 128; k4++) {
            float4 w4 = wrow[k4];
            float4 x4 = *(const float4*)&xs[tg][k4 * 4];
            acc = fmaf(w4.x, x4.x, acc); acc = fmaf(w4.y, x4.y, acc);
            acc = fmaf(w4.z, x4.z, acc); acc = fmaf(w4.w, x4.w, acc);
        }
        if (o < 96) h1s[tg][o] = fmaxf(acc, 0.f);
    }
    __syncthreads();
    // layer 2: 8 tokens x 32 outputs = 256 threads
    if (tid < 256) {
        const int tok = tid >> 5, o2 = tid & 31;
        const float* w2 = gw2 + o2 * 64;
        float a = gb2[o2];
        for (int k = 0; k < 64; k++) a = fmaf(w2[k], h1s[tok][k], a);
        h2s[tok][o2] = fmaxf(a, 0.f);
    }
    __syncthreads();
    // layer 3 + sigmoid + combine
    if (tid < 8) {
        const int tok = tid;
        float gg = gb3[0], cc = cb2[0];
        for (int k = 0; k < 32; k++) {
            gg = fmaf(gw3[k], h2s[tok][k], gg);
            cc = fmaf(cw2[k], h1s[tok][64 + k], cc);
        }
        float g = 1.f / (1.f + expf(-gg));
        float c = 1.f / (1.f + expf(-cc));
        float p1 = 0.7f * g, p2 = 0.3f * c;
        asm volatile("" : "+v"(p1), "+v"(p2));
        float comb = p1 + p2;
        float tf = ceilf(comb * 20.0f);
        tf = fminf(fmaxf(tf, 1.f), 20.f);
        Ti[tok0 + tok] = (int)tf;
        ti_out[tok0 + tok] = tf;
    }
}

// ---------------- Kernel 2: MFMA fp16 GEMM  Y = A @ B^T (+bias) ----------------
// K=512 fixed. B is [NCAT][512], Y is [M][NCAT] fp32.
// BM=BN=64, BK=32, 256 thr = 4 waves, wave-tile 32x32. Grid (NCAT/64, M/64).
template<int NCAT, bool BIAS>
__global__ __launch_bounds__(256) void k_gemm(
    const _Float16* __restrict__ A, const _Float16* __restrict__ B,
    const float* __restrict__ bias, float* __restrict__ Y)
{
    __shared__ _Float16 As[4][64][8];
    __shared__ _Float16 Bs[4][64][8];

    const int bn = blockIdx.x * 64, bm = blockIdx.y * 64;
    const int tid = threadIdx.x, w = tid >> 6, l = tid & 63;
    const int mB = (w & 1) * 32, nB = (w >> 1) * 32;
    const int sr = tid >> 2, sk = tid & 3;
    const int fr = l & 15, fk = l >> 4;

    f32x4 acc[2][2] = {};

    uint4 pA = *(const uint4*)(A + (bm + sr) * 512 + sk * 8);
    uint4 pB = *(const uint4*)(B + (bn + sr) * 512 + sk * 8);

    for (int k0 = 0; k0 < 512; k0 += 32) {
        __syncthreads();
        *(uint4*)&As[sk][sr][0] = pA;
        *(uint4*)&Bs[sk][sr][0] = pB;
        __syncthreads();
        const int kn = (k0 + 32) & 511;   // wraps harmlessly on last iter
        pA = *(const uint4*)(A + (bm + sr) * 512 + kn + sk * 8);
        pB = *(const uint4*)(B + (bn + sr) * 512 + kn + sk * 8);

        f16x8 ah[2];
#pragma unroll
        for (int mt = 0; mt < 2; mt++)
            ah[mt] = *(const f16x8*)&As[fk][mB + mt * 16 + fr][0];
#pragma unroll
        for (int nt = 0; nt < 2; nt++) {
            f16x8 bh = *(const f16x8*)&Bs[fk][nB + nt * 16 + fr][0];
#pragma unroll
            for (int mt = 0; mt < 2; mt++)
                acc[mt][nt] = __builtin_amdgcn_mfma_f32_16x16x32_f16(ah[mt], bh, acc[mt][nt], 0, 0, 0);
        }
    }

#pragma unroll
    for (int mt = 0; mt < 2; mt++) {
#pragma unroll
        for (int nt = 0; nt < 2; nt++) {
            const int j = bn + nB + nt * 16 + fr;
            float badd = BIAS ? bias[j] : 0.f;
#pragma unroll
            for (int rr = 0; rr < 4; rr++) {
                const int i = bm + mB + mt * 16 + fk * 4 + rr;
                Y[i * NCAT + j] = acc[mt][nt][rr] + badd;
            }
        }
    }
}

// ---------------- Kernel 3: LIF + ballot bit-pack + fused v_mean transpose ----------------
// grid (8, 32): blockIdx.y = bh, blockIdx.x = 64-token s-block. 256 thr = 4 waves.
__global__ __launch_bounds__(256) void k_lif(
    const float* __restrict__ qkv,           // [2048][1536]  (q|k|v per row)
    const int* __restrict__ Ti,
    const float* __restrict__ pAlpha, const float* __restrict__ pBeta,
    unsigned long long* __restrict__ qbits,  // [(bh*20)+t]*512 + s
    unsigned long long* __restrict__ kbits,
    _Float16* __restrict__ vmT)              // [bh][d][s]
{
    __shared__ _Float16 cnts[64][65];        // [d][s_local]
    const int wid = threadIdx.x >> 6, lane = threadIdx.x & 63;
    const int bh = blockIdx.y, s0 = blockIdx.x * 64;
    const int b = bh >> 3, h = bh & 7;
    const float alpha = pAlpha[0], beta = pBeta[0];

    const float* qrow0 = qkv + (b * 512 + s0 + wid) * 1536 + h * 64 + lane;
    float cq = qrow0[0], ck = qrow0[512], cv = qrow0[1024];

    for (int r = 0; r < 16; r++) {
        const int tl = r * 4 + wid;          // token_local 0..63
        const int s = s0 + tl;
        float nq = 0.f, nk = 0.f, nv = 0.f;
        if (r < 15) {
            const float* qr = qkv + (b * 512 + s0 + tl + 4) * 1536 + h * 64 + lane;
            nq = qr[0]; nk = qr[512]; nv = qr[1024];
        }
        const int T = Ti[b * 512 + s];
        float iq = 0.f, vq = 0.f, ik = 0.f, vk = 0.f, iv = 0.f, vv = 0.f;
        int cnt = 0;
        const int base = (bh * 20) * 512 + s;
#pragma unroll
        for (int t = 0; t < 20; t++) {
            iq = sep_mad(alpha, iq, cq); vq = sep_mad(beta, vq, iq);
            bool sq = vq >= 1.0f; vq = sq ? 0.f : vq;
            ik = sep_mad(alpha, ik, ck); vk = sep_mad(beta, vk, ik);
            bool sk = vk >= 1.0f; vk = sk ? 0.f : vk;
            iv = sep_mad(alpha, iv, cv); vv = sep_mad(beta, vv, iv);
            bool sv = vv >= 1.0f; vv = sv ? 0.f : vv;
            bool act = t < T;
            unsigned long long mq = __ballot(sq && act);
            unsigned long long mk = __ballot(sk && act);
            if (lane == 0) {
                qbits[base + t * 512] = mq;
                kbits[base + t * 512] = mk;
            }
            cnt += (sv && act) ? 1 : 0;
        }
        cnts[lane][tl] = (_Float16)((float)cnt / 20.0f);
        cq = nq; ck = nk; cv = nv;
    }
    __syncthreads();
    const int d = threadIdx.x >> 2, q = threadIdx.x & 3;
    HU8 o0, o1;
#pragma unroll
    for (int i = 0; i < 8; i++) {
        o0.h[i] = cnts[d][q * 16 + i];
        o1.h[i] = cnts[d][q * 16 + 8 + i];
    }
    _Float16* dst = vmT + (bh * 64 + d) * 512 + s0 + q * 16;
    *(uint4*)dst = o0.u;
    *(uint4*)(dst + 8) = o1.u;
}

// ---------------- Kernel 4: popcount scores + softmax -> attn (+fused reg) ----------------
__global__ __launch_bounds__(256) void k_scores(
    const unsigned long long* __restrict__ qbits,
    const unsigned long long* __restrict__ kbits,
    float* __restrict__ attn,
    const int* __restrict__ Ti, float* __restrict__ regp)
{
    const int bh = blockIdx.x >> 5;            // 0..31
    const int i0 = (blockIdx.x & 31) * 16;
    const int base = bh * 20 * 512;
    __shared__ unsigned long long qs[20][16];
    __shared__ float sc[16][512];
    const int tid = threadIdx.x;
    for (int idx = tid; idx < 320; idx += 256) {
        int t = idx >> 4, r = idx & 15;
        qs[t][r] = qbits[base + t * 512 + i0 + r];
    }
    int Tmax = 0;
    const int tb = (bh >> 3) * 512 + i0;
#pragma unroll
    for (int r = 0; r < 16; r++) Tmax = max(Tmax, Ti[tb + r]);
    __syncthreads();

    {
        const unsigned long long* kbp = kbits + base + tid;
        int acc0[16] = {}, acc1[16] = {};
        for (int tc = 0; tc < 4; tc++) {
            if (tc * 5 >= Tmax) break;
            unsigned long long kv0[5], kv1[5];
#pragma unroll
            for (int t = 0; t < 5; t++) {
                kv0[t] = kbp[(tc * 5 + t) * 512];
                kv1[t] = kbp[(tc * 5 + t) * 512 + 256];
            }
#pragma unroll
            for (int r = 0; r < 16; r++) {
#pragma unroll
                for (int t = 0; t < 5; t++) {
                    unsigned long long qv = qs[tc * 5 + t][r];
                    acc0[r] += __popcll(qv & kv0[t]);
                    acc1[r] += __popcll(qv & kv1[t]);
                }
            }
        }
#pragma unroll
        for (int r = 0; r < 16; r++) {
            sc[r][tid] = (float)acc0[r] * 0.125f;
            sc[r][tid + 256] = (float)acc1[r] * 0.125f;
        }
    }
    __syncthreads();

    const int wid = tid >> 6, lane = tid & 63;
#pragma unroll
    for (int rr = 0; rr < 4; rr++) {
        const int r = wid * 4 + rr;
        float vals[8];
        float m = -1e30f;
#pragma unroll
        for (int k = 0; k < 8; k++) { vals[k] = sc[r][lane + 64 * k]; m = fmaxf(m, vals[k]); }
#pragma unroll
        for (int off = 32; off; off >>= 1) m = fmaxf(m, __shfl_xor(m, off));
        float sum = 0.f;
#pragma unroll
        for (int k = 0; k < 8; k++) { vals[k] = expf(vals[k] - m); sum += vals[k]; }
#pragma unroll
        for (int off = 32; off; off >>= 1) sum += __shfl_xor(sum, off);
        float* arow = attn + ((long)bh * 512 + (i0 + r)) * 512;
#pragma unroll
        for (int k = 0; k < 8; k++) arow[lane + 64 * k] = vals[k] / sum;
    }

    if (blockIdx.x == 0 && tid < 64) {
        int s = 0;
        for (int k = tid; k < 2048; k += 64) s += Ti[k];
#pragma unroll
        for (int off = 32; off; off >>= 1) s += __shfl_xor(s, off);
        if (tid == 0) regp[0] = 1e-3f * ((float)s / 2048.0f);
    }
}

// ---------------- Kernel 5: MFMA AV  hout = attn @ v_mean  (per b,h; fp16) ----------------
__global__ __launch_bounds__(256) void k_av(
    const float* __restrict__ attn,
    const _Float16* __restrict__ vmT,   // [bh][d][s]
    _Float16* __restrict__ hout)        // [tok][h*64+d] fp16
{
    __shared__ _Float16 Aa[4][64][8];
    __shared__ _Float16 Bb[4][64][8];
    const int i0 = blockIdx.x * 64;
    const int bh = blockIdx.y;
    const int b = bh >> 3, h = bh & 7;
    const int tid = threadIdx.x, w = tid >> 6, l = tid & 63;
    const int mB = (w & 1) * 32, nB = (w >> 1) * 32;
    const int sr = tid >> 2, sk = tid & 3;
    const int fr = l & 15, fk = l >> 4;
    const float* abase = attn + ((long)bh * 512 + i0) * 512;
    const _Float16* bbase = vmT + bh * 64 * 512;

    f32x4 acc[2][2] = {};

    float4 pa0 = *(const float4*)(abase + sr * 512 + sk * 8);
    float4 pa1 = *(const float4*)(abase + sr * 512 + sk * 8 + 4);
    uint4 pb = *(const uint4*)(bbase + sr * 512 + sk * 8);

    for (int k0 = 0; k0 < 512; k0 += 32) {
        __syncthreads();
        {
            HU8 z;
            z.h[0] = (_Float16)pa0.x; z.h[1] = (_Float16)pa0.y;
            z.h[2] = (_Float16)pa0.z; z.h[3] = (_Float16)pa0.w;
            z.h[4] = (_Float16)pa1.x; z.h[5] = (_Float16)pa1.y;
            z.h[6] = (_Float16)pa1.z; z.h[7] = (_Float16)pa1.w;
            *(uint4*)&Aa[sk][sr][0] = z.u;
            *(uint4*)&Bb[sk][sr][0] = pb;
        }
        __syncthreads();
        const int kn = (k0 + 32) & 511;
        pa0 = *(const float4*)(abase + sr * 512 + kn + sk * 8);
        pa1 = *(const float4*)(abase + sr * 512 + kn + sk * 8 + 4);
        pb = *(const uint4*)(bbase + sr * 512 + kn + sk * 8);

        f16x8 ah[2];
#pragma unroll
        for (int mt = 0; mt < 2; mt++)
            ah[mt] = *(const f16x8*)&Aa[fk][mB + mt * 16 + fr][0];
#pragma unroll
        for (int nt = 0; nt < 2; nt++) {
            f16x8 bv = *(const f16x8*)&Bb[fk][nB + nt * 16 + fr][0];
#pragma unroll
            for (int mt = 0; mt < 2; mt++)
                acc[mt][nt] = __builtin_amdgcn_mfma_f32_16x16x32_f16(ah[mt], bv, acc[mt][nt], 0, 0, 0);
        }
    }

#pragma unroll
    for (int mt = 0; mt < 2; mt++) {
#pragma unroll
        for (int nt = 0; nt < 2; nt++) {
            const int d = nB + nt * 16 + fr;
#pragma unroll
            for (int rr = 0; rr < 4; rr++) {
                const int i = i0 + mB + mt * 16 + fk * 4 + rr;
                hout[(b * 512 + i) * 512 + h * 64 + d] = (_Float16)acc[mt][nt][rr];
            }
        }
    }
}

extern "C" void kernel_launch(void* const* d_in, const int* in_sizes, int n_in,
                              void* d_out, int out_size, void* d_ws, size_t ws_size,
                              hipStream_t stream)
{
    const float* x    = (const float*)d_in[0];
    const float* Wq   = (const float*)d_in[1];
    const float* Wk   = (const float*)d_in[2];
    const float* Wv   = (const float*)d_in[3];
    const float* Wo   = (const float*)d_in[4];
    const float* bo   = (const float*)d_in[5];
    const float* gw1  = (const float*)d_in[6];
    const float* gb1  = (const float*)d_in[7];
    const float* gw2  = (const float*)d_in[8];
    const float* gb2  = (const float*)d_in[9];
    const float* gw3  = (const float*)d_in[10];
    const float* gb3  = (const float*)d_in[11];
    const float* cw1  = (const float*)d_in[12];
    const float* cb1  = (const float*)d_in[13];
    const float* cw2  = (const float*)d_in[14];
    const float* cb2  = (const float*)d_in[15];
    const float* alpha = (const float*)d_in[16];
    const float* beta  = (const float*)d_in[17];

    float* out   = (float*)d_out;                 // [2048*512]
    float* attn  = out + 1048576;                 // [32][512][512]
    float* regp  = out + 1048576 + 8388608;
    float* tiout = regp + 1;

    // workspace (no aliasing, ~26.2 MB):
    char* ws = (char*)d_ws;
    float*    qkv    = (float*)ws;                            // [2048][1536] fp32, 12.58 MB
    unsigned long long* qb = (unsigned long long*)(ws + 12582912);   // 2.62 MB
    unsigned long long* kb = (unsigned long long*)(ws + 15204352);   // 2.62 MB
    _Float16* vmT    = (_Float16*)(ws + 17825792);            // [32][64][512] 2 MB
    _Float16* hout_h = (_Float16*)(ws + 19922944);            // 2 MB
    int*      Ti     = (int*)(ws + 22020096);                 // 8 KB
    _Float16* xh     = (_Float16*)(ws + 22028288);            // 2 MB
    _Float16* Wh     = (_Float16*)(ws + 24125440);            // [1536][512] 1.57 MB
    _Float16* Woh    = (_Float16*)(ws + 25698304);            // 0.52 MB

    k_convert<<<2048, 256, 0, stream>>>(x, Wq, Wk, Wv, Wo, xh, Wh, Woh);
    k_gates<<<256, 1024, 0, stream>>>(x, gw1, gb1, gw2, gb2, gw3, gb3,
                                      cw1, cb1, cw2, cb2, Ti, tiout);
    k_gemm<1536, false><<<dim3(24, 32), 256, 0, stream>>>(xh, Wh, nullptr, qkv);
    k_lif<<<dim3(8, 32), 256, 0, stream>>>(qkv, Ti, alpha, beta, qb, kb, vmT);
    k_scores<<<1024, 256, 0, stream>>>(qb, kb, attn, Ti, regp);
    k_av<<<dim3(8, 32), 256, 0, stream>>>(attn, vmT, hout_h);
    k_gemm<512, true><<<dim3(8, 32), 256, 0, stream>>>(hout_h, Woh, bo, out);
}

// Round 8
// 130.638 us; speedup vs baseline: 1.2156x; 1.2156x over previous
//
#include <hip/hip_runtime.h>
#include <cstdint>

// B=4, S=512, D=512, H=8, TM=20, DH=64
// out layout: out[1048576] | attn[8388608] | reg[1] | T_i[2048]  (all float)

typedef __attribute__((ext_vector_type(8))) _Float16 f16x8;
typedef __attribute__((ext_vector_type(4))) float f32x4;

__device__ __forceinline__ float sep_mad(float a, float b, float c) {
    // separate mul+add rounding (matches numpy), blocks FMA contraction:
    // spike threshold is discontinuous.
    float t = a * b;
    asm volatile("" : "+v"(t));
    return t + c;
}

union HU4 { _Float16 h[4]; ushort4 u; };
union HU8 { _Float16 h[8]; uint4 u; };

__device__ __forceinline__ void split4(float4 v, HU4& hi, HU4& lo) {
    hi.h[0] = (_Float16)v.x; lo.h[0] = (_Float16)(v.x - (float)hi.h[0]);
    hi.h[1] = (_Float16)v.y; lo.h[1] = (_Float16)(v.y - (float)hi.h[1]);
    hi.h[2] = (_Float16)v.z; lo.h[2] = (_Float16)(v.z - (float)hi.h[2]);
    hi.h[3] = (_Float16)v.w; lo.h[3] = (_Float16)(v.w - (float)hi.h[3]);
}

// ---------------- Kernel 0: fp32 -> fp16 hi/lo convert ----------------
// Builds: xh/xl [2048][512]; WG = [Wq|Wk|Wv|gw1|cw1|pad0] hi/lo [1664][512]; Woh [512][512].
__global__ __launch_bounds__(256) void k_convert(
    const float* __restrict__ x,
    const float* __restrict__ Wq, const float* __restrict__ Wk,
    const float* __restrict__ Wv, const float* __restrict__ Wo,
    const float* __restrict__ gw1, const float* __restrict__ cw1,
    _Float16* __restrict__ xh, _Float16* __restrict__ xl,
    _Float16* __restrict__ WGh, _Float16* __restrict__ WGl,
    _Float16* __restrict__ Woh)
{
    const int t = blockIdx.x * 256 + threadIdx.x;   // one float4 per thread
    HU4 hi, lo;
    if (t < 262144) {                                // x
        float4 v = ((const float4*)x)[t];
        split4(v, hi, lo);
        ((ushort4*)xh)[t] = hi.u;
        ((ushort4*)xl)[t] = lo.u;
        return;
    }
    const int t2 = t - 262144;
    if (t2 < 196608) {                               // Wq|Wk|Wv rows 0..1535
        const int sel = t2 >> 16, o = t2 & 65535;
        const float* src = (sel == 0) ? Wq : ((sel == 1) ? Wk : Wv);
        float4 v = ((const float4*)src)[o];
        split4(v, hi, lo);
        ((ushort4*)WGh)[t2] = hi.u;
        ((ushort4*)WGl)[t2] = lo.u;
        return;
    }
    const int t3 = t2 - 196608;
    if (t3 < 12288) {                                // gw1|cw1 rows 1536..1631
        const int row = t3 >> 7, c4 = t3 & 127;
        const float* src = (row < 64) ? (gw1 + row * 512) : (cw1 + (row - 64) * 512);
        float4 v = ((const float4*)src)[c4];
        split4(v, hi, lo);
        ((ushort4*)WGh)[196608 + t3] = hi.u;
        ((ushort4*)WGl)[196608 + t3] = lo.u;
        return;
    }
    const int t4 = t3 - 12288;
    if (t4 < 4096) {                                 // pad rows 1632..1663 = 0
        ushort4 z; z.x = z.y = z.z = z.w = 0;
        ((ushort4*)WGh)[208896 + t4] = z;
        ((ushort4*)WGl)[208896 + t4] = z;
        return;
    }
    const int t5 = t4 - 4096;                        // Wo (hi only), 65536 f4
    float4 v = ((const float4*)Wo)[t5];
    split4(v, hi, lo);
    ((ushort4*)Woh)[t5] = hi.u;
}

// ---------------- Kernel 1: unified fp16x3 MFMA GEMM  Y = A @ WG^T ----------------
// A = x (hi/lo fp16), WG = [1664][512] hi/lo. Y [2048][1664] fp32 (raw, no bias).
// BM=BN=64, BK=32, 256 thr = 4 waves wave-tile 32x32, 3 hi/lo products.
__global__ __launch_bounds__(256) void k_gemm3(
    const _Float16* __restrict__ Ah, const _Float16* __restrict__ Al,
    const _Float16* __restrict__ Bh, const _Float16* __restrict__ Bl,
    float* __restrict__ Y)
{
    __shared__ _Float16 AsH[4][64][8];
    __shared__ _Float16 BsH[4][64][8];
    __shared__ _Float16 AsL[4][64][8];
    __shared__ _Float16 BsL[4][64][8];

    const int bn = blockIdx.x * 64, bm = blockIdx.y * 64;
    const int tid = threadIdx.x, w = tid >> 6, l = tid & 63;
    const int mB = (w & 1) * 32, nB = (w >> 1) * 32;
    const int sr = tid >> 2, sk = tid & 3;
    const int fr = l & 15, fk = l >> 4;

    f32x4 acc[2][2] = {};

    uint4 pAh = *(const uint4*)(Ah + (bm + sr) * 512 + sk * 8);
    uint4 pBh = *(const uint4*)(Bh + (bn + sr) * 512 + sk * 8);
    uint4 pAl = *(const uint4*)(Al + (bm + sr) * 512 + sk * 8);
    uint4 pBl = *(const uint4*)(Bl + (bn + sr) * 512 + sk * 8);

    for (int k0 = 0; k0 < 512; k0 += 32) {
        __syncthreads();
        *(uint4*)&AsH[sk][sr][0] = pAh;
        *(uint4*)&BsH[sk][sr][0] = pBh;
        *(uint4*)&AsL[sk][sr][0] = pAl;
        *(uint4*)&BsL[sk][sr][0] = pBl;
        __syncthreads();
        const int kn = (k0 + 32) & 511;   // wraps harmlessly on last iter
        pAh = *(const uint4*)(Ah + (bm + sr) * 512 + kn + sk * 8);
        pBh = *(const uint4*)(Bh + (bn + sr) * 512 + kn + sk * 8);
        pAl = *(const uint4*)(Al + (bm + sr) * 512 + kn + sk * 8);
        pBl = *(const uint4*)(Bl + (bn + sr) * 512 + kn + sk * 8);

        f16x8 ah[2], al[2];
#pragma unroll
        for (int mt = 0; mt < 2; mt++) {
            ah[mt] = *(const f16x8*)&AsH[fk][mB + mt * 16 + fr][0];
            al[mt] = *(const f16x8*)&AsL[fk][mB + mt * 16 + fr][0];
        }
#pragma unroll
        for (int nt = 0; nt < 2; nt++) {
            f16x8 bh = *(const f16x8*)&BsH[fk][nB + nt * 16 + fr][0];
            f16x8 bl = *(const f16x8*)&BsL[fk][nB + nt * 16 + fr][0];
#pragma unroll
            for (int mt = 0; mt < 2; mt++) {
                acc[mt][nt] = __builtin_amdgcn_mfma_f32_16x16x32_f16(ah[mt], bh, acc[mt][nt], 0, 0, 0);
                acc[mt][nt] = __builtin_amdgcn_mfma_f32_16x16x32_f16(ah[mt], bl, acc[mt][nt], 0, 0, 0);
                acc[mt][nt] = __builtin_amdgcn_mfma_f32_16x16x32_f16(al[mt], bh, acc[mt][nt], 0, 0, 0);
            }
        }
    }

#pragma unroll
    for (int mt = 0; mt < 2; mt++) {
#pragma unroll
        for (int nt = 0; nt < 2; nt++) {
            const int j = bn + nB + nt * 16 + fr;
#pragma unroll
            for (int rr = 0; rr < 4; rr++) {
                const int i = bm + mB + mt * 16 + fk * 4 + rr;
                Y[i * 1664 + j] = acc[mt][nt][rr];
            }
        }
    }
}

// ---------------- Kernel 2: gate layers 2+3 -> T_i ----------------
// h1raw = qkvh1 + 1536 (stride 1664), 96 cols. 64 blocks x 256 thr, 32 tokens/block.
__global__ __launch_bounds__(256) void k_gates2(
    const float* __restrict__ h1raw,
    const float* __restrict__ gb1, const float* __restrict__ cb1,
    const float* __restrict__ gw2, const float* __restrict__ gb2,
    const float* __restrict__ gw3, const float* __restrict__ gb3,
    const float* __restrict__ cw2, const float* __restrict__ cb2,
    int* __restrict__ Ti, float* __restrict__ ti_out)
{
    __shared__ float h1s[32][100];
    __shared__ float w2s[32][65];    // 65-pad: bank = (o2 + k) & 31, conflict-free
    __shared__ float h2s[32][36];
    const int tok0 = blockIdx.x * 32;
    const int tid = threadIdx.x;

    for (int i = tid; i < 2048; i += 256) w2s[i >> 6][i & 63] = gw2[i];
    for (int i = tid; i < 3072; i += 256) {
        const int r = i / 96, c = i % 96;
        const float v = h1raw[(long)(tok0 + r) * 1664 + c] + (c < 64 ? gb1[c] : cb1[c - 64]);
        h1s[r][c] = fmaxf(v, 0.f);
    }
    __syncthreads();

#pragma unroll
    for (int it = 0; it < 4; it++) {
        const int tok = (tid >> 5) + it * 8, o2 = tid & 31;
        float a = gb2[o2];
        for (int k = 0; k < 64; k++) a = fmaf(w2s[o2][k], h1s[tok][k], a);
        h2s[tok][o2] = fmaxf(a, 0.f);
    }
    __syncthreads();

    if (tid < 32) {
        const int tok = tid;
        float gg = gb3[0], cc = cb2[0];
        for (int k = 0; k < 32; k++) {
            gg = fmaf(gw3[k], h2s[tok][k], gg);
            cc = fmaf(cw2[k], h1s[tok][64 + k], cc);
        }
        float g = 1.f / (1.f + expf(-gg));
        float c = 1.f / (1.f + expf(-cc));
        float p1 = 0.7f * g, p2 = 0.3f * c;
        asm volatile("" : "+v"(p1), "+v"(p2));
        float comb = p1 + p2;
        float tf = ceilf(comb * 20.0f);
        tf = fminf(fmaxf(tf, 1.f), 20.f);
        Ti[tok0 + tok] = (int)tf;
        ti_out[tok0 + tok] = tf;
    }
}

// ---------------- Kernel 3: MFMA fp16 GEMM (Wo projection) ----------------
template<int NCAT, bool BIAS>
__global__ __launch_bounds__(256) void k_gemm(
    const _Float16* __restrict__ A, const _Float16* __restrict__ B,
    const float* __restrict__ bias, float* __restrict__ Y)
{
    __shared__ _Float16 As[4][64][8];
    __shared__ _Float16 Bs[4][64][8];

    const int bn = blockIdx.x * 64, bm = blockIdx.y * 64;
    const int tid = threadIdx.x, w = tid >> 6, l = tid & 63;
    const int mB = (w & 1) * 32, nB = (w >> 1) * 32;
    const int sr = tid >> 2, sk = tid & 3;
    const int fr = l & 15, fk = l >> 4;

    f32x4 acc[2][2] = {};

    uint4 pA = *(const uint4*)(A + (bm + sr) * 512 + sk * 8);
    uint4 pB = *(const uint4*)(B + (bn + sr) * 512 + sk * 8);

    for (int k0 = 0; k0 < 512; k0 += 32) {
        __syncthreads();
        *(uint4*)&As[sk][sr][0] = pA;
        *(uint4*)&Bs[sk][sr][0] = pB;
        __syncthreads();
        const int kn = (k0 + 32) & 511;
        pA = *(const uint4*)(A + (bm + sr) * 512 + kn + sk * 8);
        pB = *(const uint4*)(B + (bn + sr) * 512 + kn + sk * 8);

        f16x8 ah[2];
#pragma unroll
        for (int mt = 0; mt < 2; mt++)
            ah[mt] = *(const f16x8*)&As[fk][mB + mt * 16 + fr][0];
#pragma unroll
        for (int nt = 0; nt < 2; nt++) {
            f16x8 bh = *(const f16x8*)&Bs[fk][nB + nt * 16 + fr][0];
#pragma unroll
            for (int mt = 0; mt < 2; mt++)
                acc[mt][nt] = __builtin_amdgcn_mfma_f32_16x16x32_f16(ah[mt], bh, acc[mt][nt], 0, 0, 0);
        }
    }

#pragma unroll
    for (int mt = 0; mt < 2; mt++) {
#pragma unroll
        for (int nt = 0; nt < 2; nt++) {
            const int j = bn + nB + nt * 16 + fr;
            float badd = BIAS ? bias[j] : 0.f;
#pragma unroll
            for (int rr = 0; rr < 4; rr++) {
                const int i = bm + mB + mt * 16 + fk * 4 + rr;
                Y[i * NCAT + j] = acc[mt][nt][rr] + badd;
            }
        }
    }
}

// ---------------- Kernel 4: LIF + ballot bit-pack + fused v_mean transpose ----------------
__global__ __launch_bounds__(256) void k_lif(
    const float* __restrict__ qkv,           // [2048][1664]  (q|k|v|h1 per row)
    const int* __restrict__ Ti,
    const float* __restrict__ pAlpha, const float* __restrict__ pBeta,
    unsigned long long* __restrict__ qbits,  // [(bh*20)+t]*512 + s
    unsigned long long* __restrict__ kbits,
    _Float16* __restrict__ vmT)              // [bh][d][s]
{
    __shared__ _Float16 cnts[64][65];        // [d][s_local]
    const int wid = threadIdx.x >> 6, lane = threadIdx.x & 63;
    const int bh = blockIdx.y, s0 = blockIdx.x * 64;
    const int b = bh >> 3, h = bh & 7;
    const float alpha = pAlpha[0], beta = pBeta[0];

    const float* qrow0 = qkv + (long)(b * 512 + s0 + wid) * 1664 + h * 64 + lane;
    float cq = qrow0[0], ck = qrow0[512], cv = qrow0[1024];

    for (int r = 0; r < 16; r++) {
        const int tl = r * 4 + wid;          // token_local 0..63
        const int s = s0 + tl;
        float nq = 0.f, nk = 0.f, nv = 0.f;
        if (r < 15) {
            const float* qr = qkv + (long)(b * 512 + s0 + tl + 4) * 1664 + h * 64 + lane;
            nq = qr[0]; nk = qr[512]; nv = qr[1024];
        }
        const int T = Ti[b * 512 + s];
        float iq = 0.f, vq = 0.f, ik = 0.f, vk = 0.f, iv = 0.f, vv = 0.f;
        int cnt = 0;
        const int base = (bh * 20) * 512 + s;
#pragma unroll
        for (int t = 0; t < 20; t++) {
            iq = sep_mad(alpha, iq, cq); vq = sep_mad(beta, vq, iq);
            bool sq = vq >= 1.0f; vq = sq ? 0.f : vq;
            ik = sep_mad(alpha, ik, ck); vk = sep_mad(beta, vk, ik);
            bool sk = vk >= 1.0f; vk = sk ? 0.f : vk;
            iv = sep_mad(alpha, iv, cv); vv = sep_mad(beta, vv, iv);
            bool sv = vv >= 1.0f; vv = sv ? 0.f : vv;
            bool act = t < T;
            unsigned long long mq = __ballot(sq && act);
            unsigned long long mk = __ballot(sk && act);
            if (lane == 0) {
                qbits[base + t * 512] = mq;
                kbits[base + t * 512] = mk;
            }
            cnt += (sv && act) ? 1 : 0;
        }
        cnts[lane][tl] = (_Float16)((float)cnt / 20.0f);
        cq = nq; ck = nk; cv = nv;
    }
    __syncthreads();
    const int d = threadIdx.x >> 2, q = threadIdx.x & 3;
    HU8 o0, o1;
#pragma unroll
    for (int i = 0; i < 8; i++) {
        o0.h[i] = cnts[d][q * 16 + i];
        o1.h[i] = cnts[d][q * 16 + 8 + i];
    }
    _Float16* dst = vmT + (bh * 64 + d) * 512 + s0 + q * 16;
    *(uint4*)dst = o0.u;
    *(uint4*)(dst + 8) = o1.u;
}

// ---------------- Kernel 5: popcount scores + softmax -> attn (+fused reg) ----------------
__global__ __launch_bounds__(256) void k_scores(
    const unsigned long long* __restrict__ qbits,
    const unsigned long long* __restrict__ kbits,
    float* __restrict__ attn,
    const int* __restrict__ Ti, float* __restrict__ regp)
{
    const int bh = blockIdx.x >> 5;            // 0..31
    const int i0 = (blockIdx.x & 31) * 16;
    const int base = bh * 20 * 512;
    __shared__ unsigned long long qs[20][16];
    __shared__ float sc[16][512];
    const int tid = threadIdx.x;
    for (int idx = tid; idx < 320; idx += 256) {
        int t = idx >> 4, r = idx & 15;
        qs[t][r] = qbits[base + t * 512 + i0 + r];
    }
    int Tmax = 0;
    const int tb = (bh >> 3) * 512 + i0;
#pragma unroll
    for (int r = 0; r < 16; r++) Tmax = max(Tmax, Ti[tb + r]);
    __syncthreads();

    {
        const unsigned long long* kbp = kbits + base + tid;
        int acc0[16] = {}, acc1[16] = {};
        for (int tc = 0; tc < 4; tc++) {
            if (tc * 5 >= Tmax) break;
            unsigned long long kv0[5], kv1[5];
#pragma unroll
            for (int t = 0; t < 5; t++) {
                kv0[t] = kbp[(tc * 5 + t) * 512];
                kv1[t] = kbp[(tc * 5 + t) * 512 + 256];
            }
#pragma unroll
            for (int r = 0; r < 16; r++) {
#pragma unroll
                for (int t = 0; t < 5; t++) {
                    unsigned long long qv = qs[tc * 5 + t][r];
                    acc0[r] += __popcll(qv & kv0[t]);
                    acc1[r] += __popcll(qv & kv1[t]);
                }
            }
        }
#pragma unroll
        for (int r = 0; r < 16; r++) {
            sc[r][tid] = (float)acc0[r] * 0.125f;
            sc[r][tid + 256] = (float)acc1[r] * 0.125f;
        }
    }
    __syncthreads();

    const int wid = tid >> 6, lane = tid & 63;
#pragma unroll
    for (int rr = 0; rr < 4; rr++) {
        const int r = wid * 4 + rr;
        float vals[8];
        float m = -1e30f;
#pragma unroll
        for (int k = 0; k < 8; k++) { vals[k] = sc[r][lane + 64 * k]; m = fmaxf(m, vals[k]); }
#pragma unroll
        for (int off = 32; off; off >>= 1) m = fmaxf(m, __shfl_xor(m, off));
        float sum = 0.f;
#pragma unroll
        for (int k = 0; k < 8; k++) { vals[k] = expf(vals[k] - m); sum += vals[k]; }
#pragma unroll
        for (int off = 32; off; off >>= 1) sum += __shfl_xor(sum, off);
        float* arow = attn + ((long)bh * 512 + (i0 + r)) * 512;
#pragma unroll
        for (int k = 0; k < 8; k++) arow[lane + 64 * k] = vals[k] / sum;
    }

    if (blockIdx.x == 0 && tid < 64) {
        int s = 0;
        for (int k = tid; k < 2048; k += 64) s += Ti[k];
#pragma unroll
        for (int off = 32; off; off >>= 1) s += __shfl_xor(s, off);
        if (tid == 0) regp[0] = 1e-3f * ((float)s / 2048.0f);
    }
}

// ---------------- Kernel 6: MFMA AV  hout = attn @ v_mean  (per b,h; fp16) ----------------
__global__ __launch_bounds__(256) void k_av(
    const float* __restrict__ attn,
    const _Float16* __restrict__ vmT,   // [bh][d][s]
    _Float16* __restrict__ hout)        // [tok][h*64+d] fp16
{
    __shared__ _Float16 Aa[4][64][8];
    __shared__ _Float16 Bb[4][64][8];
    const int i0 = blockIdx.x * 64;
    const int bh = blockIdx.y;
    const int b = bh >> 3, h = bh & 7;
    const int tid = threadIdx.x, w = tid >> 6, l = tid & 63;
    const int mB = (w & 1) * 32, nB = (w >> 1) * 32;
    const int sr = tid >> 2, sk = tid & 3;
    const int fr = l & 15, fk = l >> 4;
    const float* abase = attn + ((long)bh * 512 + i0) * 512;
    const _Float16* bbase = vmT + bh * 64 * 512;

    f32x4 acc[2][2] = {};

    float4 pa0 = *(const float4*)(abase + sr * 512 + sk * 8);
    float4 pa1 = *(const float4*)(abase + sr * 512 + sk * 8 + 4);
    uint4 pb = *(const uint4*)(bbase + sr * 512 + sk * 8);

    for (int k0 = 0; k0 < 512; k0 += 32) {
        __syncthreads();
        {
            HU8 z;
            z.h[0] = (_Float16)pa0.x; z.h[1] = (_Float16)pa0.y;
            z.h[2] = (_Float16)pa0.z; z.h[3] = (_Float16)pa0.w;
            z.h[4] = (_Float16)pa1.x; z.h[5] = (_Float16)pa1.y;
            z.h[6] = (_Float16)pa1.z; z.h[7] = (_Float16)pa1.w;
            *(uint4*)&Aa[sk][sr][0] = z.u;
            *(uint4*)&Bb[sk][sr][0] = pb;
        }
        __syncthreads();
        const int kn = (k0 + 32) & 511;
        pa0 = *(const float4*)(abase + sr * 512 + kn + sk * 8);
        pa1 = *(const float4*)(abase + sr * 512 + kn + sk * 8 + 4);
        pb = *(const uint4*)(bbase + sr * 512 + kn + sk * 8);

        f16x8 ah[2];
#pragma unroll
        for (int mt = 0; mt < 2; mt++)
            ah[mt] = *(const f16x8*)&Aa[fk][mB + mt * 16 + fr][0];
#pragma unroll
        for (int nt = 0; nt < 2; nt++) {
            f16x8 bv = *(const f16x8*)&Bb[fk][nB + nt * 16 + fr][0];
#pragma unroll
            for (int mt = 0; mt < 2; mt++)
                acc[mt][nt] = __builtin_amdgcn_mfma_f32_16x16x32_f16(ah[mt], bv, acc[mt][nt], 0, 0, 0);
        }
    }

#pragma unroll
    for (int mt = 0; mt < 2; mt++) {
#pragma unroll
        for (int nt = 0; nt < 2; nt++) {
            const int d = nB + nt * 16 + fr;
#pragma unroll
            for (int rr = 0; rr < 4; rr++) {
                const int i = i0 + mB + mt * 16 + fk * 4 + rr;
                hout[(b * 512 + i) * 512 + h * 64 + d] = (_Float16)acc[mt][nt][rr];
            }
        }
    }
}

extern "C" void kernel_launch(void* const* d_in, const int* in_sizes, int n_in,
                              void* d_out, int out_size, void* d_ws, size_t ws_size,
                              hipStream_t stream)
{
    const float* x    = (const float*)d_in[0];
    const float* Wq   = (const float*)d_in[1];
    const float* Wk   = (const float*)d_in[2];
    const float* Wv   = (const float*)d_in[3];
    const float* Wo   = (const float*)d_in[4];
    const float* bo   = (const float*)d_in[5];
    const float* gw1  = (const float*)d_in[6];
    const float* gb1  = (const float*)d_in[7];
    const float* gw2  = (const float*)d_in[8];
    const float* gb2  = (const float*)d_in[9];
    const float* gw3  = (const float*)d_in[10];
    const float* gb3  = (const float*)d_in[11];
    const float* cw1  = (const float*)d_in[12];
    const float* cb1  = (const float*)d_in[13];
    const float* cw2  = (const float*)d_in[14];
    const float* cb2  = (const float*)d_in[15];
    const float* alpha = (const float*)d_in[16];
    const float* beta  = (const float*)d_in[17];

    float* out   = (float*)d_out;                 // [2048*512]
    float* attn  = out + 1048576;                 // [32][512][512]
    float* regp  = out + 1048576 + 8388608;
    float* tiout = regp + 1;

    // workspace (~31.2 MB, no aliasing):
    char* ws = (char*)d_ws;
    float*    qkvh1  = (float*)ws;                            // [2048][1664] fp32, 13.63 MB
    unsigned long long* qb = (unsigned long long*)(ws + 13631488);   // 2.62 MB
    unsigned long long* kb = (unsigned long long*)(ws + 16252928);   // 2.62 MB
    _Float16* vmT    = (_Float16*)(ws + 18874368);            // 2 MB
    _Float16* hout_h = (_Float16*)(ws + 20971520);            // 2 MB
    int*      Ti     = (int*)(ws + 23068672);                 // 8 KB
    _Float16* xh     = (_Float16*)(ws + 23076864);            // 2 MB
    _Float16* xl     = (_Float16*)(ws + 25174016);            // 2 MB
    _Float16* WGh    = (_Float16*)(ws + 27271168);            // [1664][512] 1.70 MB
    _Float16* WGl    = (_Float16*)(ws + 28975104);            // 1.70 MB
    _Float16* Woh    = (_Float16*)(ws + 30679040);            // 0.52 MB

    k_convert<<<2112, 256, 0, stream>>>(x, Wq, Wk, Wv, Wo, gw1, cw1,
                                        xh, xl, WGh, WGl, Woh);
    k_gemm3<<<dim3(26, 32), 256, 0, stream>>>(xh, xl, WGh, WGl, qkvh1);
    k_gates2<<<64, 256, 0, stream>>>(qkvh1 + 1536, gb1, cb1, gw2, gb2, gw3, gb3,
                                     cw2, cb2, Ti, tiout);
    k_lif<<<dim3(8, 32), 256, 0, stream>>>(qkvh1, Ti, alpha, beta, qb, kb, vmT);
    k_scores<<<1024, 256, 0, stream>>>(qb, kb, attn, Ti, regp);
    k_av<<<dim3(8, 32), 256, 0, stream>>>(attn, vmT, hout_h);
    k_gemm<512, true><<<dim3(8, 32), 256, 0, stream>>>(hout_h, Woh, bo, out);
}

// Round 9
// 114.238 us; speedup vs baseline: 1.3901x; 1.1436x over previous
//
#include <hip/hip_runtime.h>
#include <cstdint>

// B=4, S=512, D=512, H=8, TM=20, DH=64
// out layout: out[1048576] | attn[8388608] | reg[1] | T_i[2048]  (all float)

typedef __attribute__((ext_vector_type(8))) _Float16 f16x8;
typedef __attribute__((ext_vector_type(4))) float f32x4;

__device__ __forceinline__ float sep_mad(float a, float b, float c) {
    // separate mul+add rounding (matches numpy), blocks FMA contraction:
    // spike threshold is discontinuous.
    float t = a * b;
    asm volatile("" : "+v"(t));
    return t + c;
}

union HU4 { _Float16 h[4]; ushort4 u; };
union HU8 { _Float16 h[8]; uint4 u; };

__device__ __forceinline__ void split4(float4 v, HU4& hi, HU4& lo) {
    hi.h[0] = (_Float16)v.x; lo.h[0] = (_Float16)(v.x - (float)hi.h[0]);
    hi.h[1] = (_Float16)v.y; lo.h[1] = (_Float16)(v.y - (float)hi.h[1]);
    hi.h[2] = (_Float16)v.z; lo.h[2] = (_Float16)(v.z - (float)hi.h[2]);
    hi.h[3] = (_Float16)v.w; lo.h[3] = (_Float16)(v.w - (float)hi.h[3]);
}

// ---------------- Kernel 0: fp32 -> fp16 hi/lo convert ----------------
// Builds: xh/xl [2048][512]; WG = [Wq|Wk|Wv|gw1|cw1|pad0] hi/lo [1664][512]; Woh [512][512].
__global__ __launch_bounds__(256) void k_convert(
    const float* __restrict__ x,
    const float* __restrict__ Wq, const float* __restrict__ Wk,
    const float* __restrict__ Wv, const float* __restrict__ Wo,
    const float* __restrict__ gw1, const float* __restrict__ cw1,
    _Float16* __restrict__ xh, _Float16* __restrict__ xl,
    _Float16* __restrict__ WGh, _Float16* __restrict__ WGl,
    _Float16* __restrict__ Woh)
{
    const int t = blockIdx.x * 256 + threadIdx.x;   // one float4 per thread
    HU4 hi, lo;
    if (t < 262144) {                                // x
        float4 v = ((const float4*)x)[t];
        split4(v, hi, lo);
        ((ushort4*)xh)[t] = hi.u;
        ((ushort4*)xl)[t] = lo.u;
        return;
    }
    const int t2 = t - 262144;
    if (t2 < 196608) {                               // Wq|Wk|Wv rows 0..1535
        const int sel = t2 >> 16, o = t2 & 65535;
        const float* src = (sel == 0) ? Wq : ((sel == 1) ? Wk : Wv);
        float4 v = ((const float4*)src)[o];
        split4(v, hi, lo);
        ((ushort4*)WGh)[t2] = hi.u;
        ((ushort4*)WGl)[t2] = lo.u;
        return;
    }
    const int t3 = t2 - 196608;
    if (t3 < 12288) {                                // gw1|cw1 rows 1536..1631
        const int row = t3 >> 7, c4 = t3 & 127;
        const float* src = (row < 64) ? (gw1 + row * 512) : (cw1 + (row - 64) * 512);
        float4 v = ((const float4*)src)[c4];
        split4(v, hi, lo);
        ((ushort4*)WGh)[196608 + t3] = hi.u;
        ((ushort4*)WGl)[196608 + t3] = lo.u;
        return;
    }
    const int t4 = t3 - 12288;
    if (t4 < 4096) {                                 // pad rows 1632..1663 = 0
        ushort4 z; z.x = z.y = z.z = z.w = 0;
        ((ushort4*)WGh)[208896 + t4] = z;
        ((ushort4*)WGl)[208896 + t4] = z;
        return;
    }
    const int t5 = t4 - 4096;                        // Wo (hi only), 65536 f4
    float4 v = ((const float4*)Wo)[t5];
    split4(v, hi, lo);
    ((ushort4*)Woh)[t5] = hi.u;
}

// ---------------- Kernel 1: unified fp16x3 MFMA GEMM  Y = A @ WG^T ----------------
// A = x (hi/lo fp16), WG = [1664][512] hi/lo. Y [2048][1664] fp32 (raw, no bias).
// BM=BN=64, BK=32, 256 thr = 4 waves wave-tile 32x32, 3 hi/lo products.
__global__ __launch_bounds__(256) void k_gemm3(
    const _Float16* __restrict__ Ah, const _Float16* __restrict__ Al,
    const _Float16* __restrict__ Bh, const _Float16* __restrict__ Bl,
    float* __restrict__ Y)
{
    __shared__ _Float16 AsH[4][64][8];
    __shared__ _Float16 BsH[4][64][8];
    __shared__ _Float16 AsL[4][64][8];
    __shared__ _Float16 BsL[4][64][8];

    const int bn = blockIdx.x * 64, bm = blockIdx.y * 64;
    const int tid = threadIdx.x, w = tid >> 6, l = tid & 63;
    const int mB = (w & 1) * 32, nB = (w >> 1) * 32;
    const int sr = tid >> 2, sk = tid & 3;
    const int fr = l & 15, fk = l >> 4;

    f32x4 acc[2][2] = {};

    uint4 pAh = *(const uint4*)(Ah + (bm + sr) * 512 + sk * 8);
    uint4 pBh = *(const uint4*)(Bh + (bn + sr) * 512 + sk * 8);
    uint4 pAl = *(const uint4*)(Al + (bm + sr) * 512 + sk * 8);
    uint4 pBl = *(const uint4*)(Bl + (bn + sr) * 512 + sk * 8);

    for (int k0 = 0; k0 < 512; k0 += 32) {
        __syncthreads();
        *(uint4*)&AsH[sk][sr][0] = pAh;
        *(uint4*)&BsH[sk][sr][0] = pBh;
        *(uint4*)&AsL[sk][sr][0] = pAl;
        *(uint4*)&BsL[sk][sr][0] = pBl;
        __syncthreads();
        const int kn = (k0 + 32) & 511;   // wraps harmlessly on last iter
        pAh = *(const uint4*)(Ah + (bm + sr) * 512 + kn + sk * 8);
        pBh = *(const uint4*)(Bh + (bn + sr) * 512 + kn + sk * 8);
        pAl = *(const uint4*)(Al + (bm + sr) * 512 + kn + sk * 8);
        pBl = *(const uint4*)(Bl + (bn + sr) * 512 + kn + sk * 8);

        f16x8 ah[2], al[2];
#pragma unroll
        for (int mt = 0; mt < 2; mt++) {
            ah[mt] = *(const f16x8*)&AsH[fk][mB + mt * 16 + fr][0];
            al[mt] = *(const f16x8*)&AsL[fk][mB + mt * 16 + fr][0];
        }
#pragma unroll
        for (int nt = 0; nt < 2; nt++) {
            f16x8 bh = *(const f16x8*)&BsH[fk][nB + nt * 16 + fr][0];
            f16x8 bl = *(const f16x8*)&BsL[fk][nB + nt * 16 + fr][0];
#pragma unroll
            for (int mt = 0; mt < 2; mt++) {
                acc[mt][nt] = __builtin_amdgcn_mfma_f32_16x16x32_f16(ah[mt], bh, acc[mt][nt], 0, 0, 0);
                acc[mt][nt] = __builtin_amdgcn_mfma_f32_16x16x32_f16(ah[mt], bl, acc[mt][nt], 0, 0, 0);
                acc[mt][nt] = __builtin_amdgcn_mfma_f32_16x16x32_f16(al[mt], bh, acc[mt][nt], 0, 0, 0);
            }
        }
    }

#pragma unroll
    for (int mt = 0; mt < 2; mt++) {
#pragma unroll
        for (int nt = 0; nt < 2; nt++) {
            const int j = bn + nB + nt * 16 + fr;
#pragma unroll
            for (int rr = 0; rr < 4; rr++) {
                const int i = bm + mB + mt * 16 + fk * 4 + rr;
                Y[i * 1664 + j] = acc[mt][nt][rr];
            }
        }
    }
}

// ---------------- Kernel 2: gate layers 2+3 -> T_i ----------------
// h1raw = qkvh1 + 1536 (stride 1664), 96 cols. 64 blocks x 256 thr, 32 tokens/block.
__global__ __launch_bounds__(256) void k_gates2(
    const float* __restrict__ h1raw,
    const float* __restrict__ gb1, const float* __restrict__ cb1,
    const float* __restrict__ gw2, const float* __restrict__ gb2,
    const float* __restrict__ gw3, const float* __restrict__ gb3,
    const float* __restrict__ cw2, const float* __restrict__ cb2,
    int* __restrict__ Ti, float* __restrict__ ti_out)
{
    __shared__ float h1s[32][100];
    __shared__ float w2s[32][65];    // 65-pad: bank = (o2 + k) & 31, conflict-free
    __shared__ float h2s[32][36];
    const int tok0 = blockIdx.x * 32;
    const int tid = threadIdx.x;

    for (int i = tid; i < 2048; i += 256) w2s[i >> 6][i & 63] = gw2[i];
    for (int i = tid; i < 3072; i += 256) {
        const int r = i / 96, c = i % 96;
        const float v = h1raw[(long)(tok0 + r) * 1664 + c] + (c < 64 ? gb1[c] : cb1[c - 64]);
        h1s[r][c] = fmaxf(v, 0.f);
    }
    __syncthreads();

#pragma unroll
    for (int it = 0; it < 4; it++) {
        const int tok = (tid >> 5) + it * 8, o2 = tid & 31;
        float a = gb2[o2];
        for (int k = 0; k < 64; k++) a = fmaf(w2s[o2][k], h1s[tok][k], a);
        h2s[tok][o2] = fmaxf(a, 0.f);
    }
    __syncthreads();

    if (tid < 32) {
        const int tok = tid;
        float gg = gb3[0], cc = cb2[0];
        for (int k = 0; k < 32; k++) {
            gg = fmaf(gw3[k], h2s[tok][k], gg);
            cc = fmaf(cw2[k], h1s[tok][64 + k], cc);
        }
        float g = 1.f / (1.f + expf(-gg));
        float c = 1.f / (1.f + expf(-cc));
        float p1 = 0.7f * g, p2 = 0.3f * c;
        asm volatile("" : "+v"(p1), "+v"(p2));
        float comb = p1 + p2;
        float tf = ceilf(comb * 20.0f);
        tf = fminf(fmaxf(tf, 1.f), 20.f);
        Ti[tok0 + tok] = (int)tf;
        ti_out[tok0 + tok] = tf;
    }
}

// ---------------- Kernel 3: MFMA fp16 GEMM (Wo projection) ----------------
template<int NCAT, bool BIAS>
__global__ __launch_bounds__(256) void k_gemm(
    const _Float16* __restrict__ A, const _Float16* __restrict__ B,
    const float* __restrict__ bias, float* __restrict__ Y)
{
    __shared__ _Float16 As[4][64][8];
    __shared__ _Float16 Bs[4][64][8];

    const int bn = blockIdx.x * 64, bm = blockIdx.y * 64;
    const int tid = threadIdx.x, w = tid >> 6, l = tid & 63;
    const int mB = (w & 1) * 32, nB = (w >> 1) * 32;
    const int sr = tid >> 2, sk = tid & 3;
    const int fr = l & 15, fk = l >> 4;

    f32x4 acc[2][2] = {};

    uint4 pA = *(const uint4*)(A + (bm + sr) * 512 + sk * 8);
    uint4 pB = *(const uint4*)(B + (bn + sr) * 512 + sk * 8);

    for (int k0 = 0; k0 < 512; k0 += 32) {
        __syncthreads();
        *(uint4*)&As[sk][sr][0] = pA;
        *(uint4*)&Bs[sk][sr][0] = pB;
        __syncthreads();
        const int kn = (k0 + 32) & 511;
        pA = *(const uint4*)(A + (bm + sr) * 512 + kn + sk * 8);
        pB = *(const uint4*)(B + (bn + sr) * 512 + kn + sk * 8);

        f16x8 ah[2];
#pragma unroll
        for (int mt = 0; mt < 2; mt++)
            ah[mt] = *(const f16x8*)&As[fk][mB + mt * 16 + fr][0];
#pragma unroll
        for (int nt = 0; nt < 2; nt++) {
            f16x8 bh = *(const f16x8*)&Bs[fk][nB + nt * 16 + fr][0];
#pragma unroll
            for (int mt = 0; mt < 2; mt++)
                acc[mt][nt] = __builtin_amdgcn_mfma_f32_16x16x32_f16(ah[mt], bh, acc[mt][nt], 0, 0, 0);
        }
    }

#pragma unroll
    for (int mt = 0; mt < 2; mt++) {
#pragma unroll
        for (int nt = 0; nt < 2; nt++) {
            const int j = bn + nB + nt * 16 + fr;
            float badd = BIAS ? bias[j] : 0.f;
#pragma unroll
            for (int rr = 0; rr < 4; rr++) {
                const int i = bm + mB + mt * 16 + fk * 4 + rr;
                Y[i * NCAT + j] = acc[mt][nt][rr] + badd;
            }
        }
    }
}

// ---------------- Kernel 4: LIF + ballot bit-pack + fused v_mean transpose ----------------
// grid (32, 32): blockIdx.y = bh, blockIdx.x = 16-token s-block. 256 thr = 4 waves,
// 4 rounds of 4 tokens each -> 1024 blocks (4 blocks/CU) for latency hiding.
__global__ __launch_bounds__(256) void k_lif(
    const float* __restrict__ qkv,           // [2048][1664]  (q|k|v|h1 per row)
    const int* __restrict__ Ti,
    const float* __restrict__ pAlpha, const float* __restrict__ pBeta,
    unsigned long long* __restrict__ qbits,  // [(bh*20)+t]*512 + s
    unsigned long long* __restrict__ kbits,
    _Float16* __restrict__ vmT)              // [bh][d][s]
{
    __shared__ _Float16 cnts[64][18];        // [d][s_local 0..15], pad 18 (<=2-way, free)
    const int wid = threadIdx.x >> 6, lane = threadIdx.x & 63;
    const int bh = blockIdx.y, s0 = blockIdx.x * 16;
    const int b = bh >> 3, h = bh & 7;
    const float alpha = pAlpha[0], beta = pBeta[0];

    const float* qrow0 = qkv + (long)(b * 512 + s0 + wid) * 1664 + h * 64 + lane;
    float cq = qrow0[0], ck = qrow0[512], cv = qrow0[1024];

    for (int r = 0; r < 4; r++) {
        const int tl = r * 4 + wid;          // token_local 0..15
        const int s = s0 + tl;
        float nq = 0.f, nk = 0.f, nv = 0.f;
        if (r < 3) {
            const float* qr = qkv + (long)(b * 512 + s + 4) * 1664 + h * 64 + lane;
            nq = qr[0]; nk = qr[512]; nv = qr[1024];
        }
        const int T = Ti[b * 512 + s];
        float iq = 0.f, vq = 0.f, ik = 0.f, vk = 0.f, iv = 0.f, vv = 0.f;
        int cnt = 0;
        const int base = (bh * 20) * 512 + s;
#pragma unroll
        for (int t = 0; t < 20; t++) {
            iq = sep_mad(alpha, iq, cq); vq = sep_mad(beta, vq, iq);
            bool sq = vq >= 1.0f; vq = sq ? 0.f : vq;
            ik = sep_mad(alpha, ik, ck); vk = sep_mad(beta, vk, ik);
            bool sk = vk >= 1.0f; vk = sk ? 0.f : vk;
            iv = sep_mad(alpha, iv, cv); vv = sep_mad(beta, vv, iv);
            bool sv = vv >= 1.0f; vv = sv ? 0.f : vv;
            bool act = t < T;
            unsigned long long mq = __ballot(sq && act);
            unsigned long long mk = __ballot(sk && act);
            if (lane == 0) {
                qbits[base + t * 512] = mq;
                kbits[base + t * 512] = mk;
            }
            cnt += (sv && act) ? 1 : 0;
        }
        cnts[lane][tl] = (_Float16)((float)cnt / 20.0f);
        cq = nq; ck = nk; cv = nv;
    }
    __syncthreads();
    // write vmT[bh][d][s0..s0+15]: thread (d = tid>>2, q = tid&3) -> 4 fp16 = 8B
    const int d = threadIdx.x >> 2, q = threadIdx.x & 3;
    HU4 o;
#pragma unroll
    for (int i = 0; i < 4; i++) o.h[i] = cnts[d][q * 4 + i];
    *(ushort4*)(vmT + (bh * 64 + d) * 512 + s0 + q * 4) = o.u;
}

// ---------------- Kernel 5: popcount scores + softmax -> attn (+fused reg) ----------------
__global__ __launch_bounds__(256) void k_scores(
    const unsigned long long* __restrict__ qbits,
    const unsigned long long* __restrict__ kbits,
    float* __restrict__ attn,
    const int* __restrict__ Ti, float* __restrict__ regp)
{
    const int bh = blockIdx.x >> 5;            // 0..31
    const int i0 = (blockIdx.x & 31) * 16;
    const int base = bh * 20 * 512;
    __shared__ unsigned long long qs[20][16];
    __shared__ float sc[16][512];
    const int tid = threadIdx.x;
    for (int idx = tid; idx < 320; idx += 256) {
        int t = idx >> 4, r = idx & 15;
        qs[t][r] = qbits[base + t * 512 + i0 + r];
    }
    int Tmax = 0;
    const int tb = (bh >> 3) * 512 + i0;
#pragma unroll
    for (int r = 0; r < 16; r++) Tmax = max(Tmax, Ti[tb + r]);
    __syncthreads();

    {
        const unsigned long long* kbp = kbits + base + tid;
        int acc0[16] = {}, acc1[16] = {};
        for (int tc = 0; tc < 4; tc++) {
            if (tc * 5 >= Tmax) break;
            unsigned long long kv0[5], kv1[5];
#pragma unroll
            for (int t = 0; t < 5; t++) {
                kv0[t] = kbp[(tc * 5 + t) * 512];
                kv1[t] = kbp[(tc * 5 + t) * 512 + 256];
            }
#pragma unroll
            for (int r = 0; r < 16; r++) {
#pragma unroll
                for (int t = 0; t < 5; t++) {
                    unsigned long long qv = qs[tc * 5 + t][r];
                    acc0[r] += __popcll(qv & kv0[t]);
                    acc1[r] += __popcll(qv & kv1[t]);
                }
            }
        }
#pragma unroll
        for (int r = 0; r < 16; r++) {
            sc[r][tid] = (float)acc0[r] * 0.125f;
            sc[r][tid + 256] = (float)acc1[r] * 0.125f;
        }
    }
    __syncthreads();

    const int wid = tid >> 6, lane = tid & 63;
#pragma unroll
    for (int rr = 0; rr < 4; rr++) {
        const int r = wid * 4 + rr;
        float vals[8];
        float m = -1e30f;
#pragma unroll
        for (int k = 0; k < 8; k++) { vals[k] = sc[r][lane + 64 * k]; m = fmaxf(m, vals[k]); }
#pragma unroll
        for (int off = 32; off; off >>= 1) m = fmaxf(m, __shfl_xor(m, off));
        float sum = 0.f;
#pragma unroll
        for (int k = 0; k < 8; k++) { vals[k] = expf(vals[k] - m); sum += vals[k]; }
#pragma unroll
        for (int off = 32; off; off >>= 1) sum += __shfl_xor(sum, off);
        float* arow = attn + ((long)bh * 512 + (i0 + r)) * 512;
#pragma unroll
        for (int k = 0; k < 8; k++) arow[lane + 64 * k] = vals[k] / sum;
    }

    if (blockIdx.x == 0 && tid < 64) {
        int s = 0;
        for (int k = tid; k < 2048; k += 64) s += Ti[k];
#pragma unroll
        for (int off = 32; off; off >>= 1) s += __shfl_xor(s, off);
        if (tid == 0) regp[0] = 1e-3f * ((float)s / 2048.0f);
    }
}

// ---------------- Kernel 6: MFMA AV  hout = attn @ v_mean  (per b,h; fp16) ----------------
__global__ __launch_bounds__(256) void k_av(
    const float* __restrict__ attn,
    const _Float16* __restrict__ vmT,   // [bh][d][s]
    _Float16* __restrict__ hout)        // [tok][h*64+d] fp16
{
    __shared__ _Float16 Aa[4][64][8];
    __shared__ _Float16 Bb[4][64][8];
    const int i0 = blockIdx.x * 64;
    const int bh = blockIdx.y;
    const int b = bh >> 3, h = bh & 7;
    const int tid = threadIdx.x, w = tid >> 6, l = tid & 63;
    const int mB = (w & 1) * 32, nB = (w >> 1) * 32;
    const int sr = tid >> 2, sk = tid & 3;
    const int fr = l & 15, fk = l >> 4;
    const float* abase = attn + ((long)bh * 512 + i0) * 512;
    const _Float16* bbase = vmT + bh * 64 * 512;

    f32x4 acc[2][2] = {};

    float4 pa0 = *(const float4*)(abase + sr * 512 + sk * 8);
    float4 pa1 = *(const float4*)(abase + sr * 512 + sk * 8 + 4);
    uint4 pb = *(const uint4*)(bbase + sr * 512 + sk * 8);

    for (int k0 = 0; k0 < 512; k0 += 32) {
        __syncthreads();
        {
            HU8 z;
            z.h[0] = (_Float16)pa0.x; z.h[1] = (_Float16)pa0.y;
            z.h[2] = (_Float16)pa0.z; z.h[3] = (_Float16)pa0.w;
            z.h[4] = (_Float16)pa1.x; z.h[5] = (_Float16)pa1.y;
            z.h[6] = (_Float16)pa1.z; z.h[7] = (_Float16)pa1.w;
            *(uint4*)&Aa[sk][sr][0] = z.u;
            *(uint4*)&Bb[sk][sr][0] = pb;
        }
        __syncthreads();
        const int kn = (k0 + 32) & 511;
        pa0 = *(const float4*)(abase + sr * 512 + kn + sk * 8);
        pa1 = *(const float4*)(abase + sr * 512 + kn + sk * 8 + 4);
        pb = *(const uint4*)(bbase + sr * 512 + kn + sk * 8);

        f16x8 ah[2];
#pragma unroll
        for (int mt = 0; mt < 2; mt++)
            ah[mt] = *(const f16x8*)&Aa[fk][mB + mt * 16 + fr][0];
#pragma unroll
        for (int nt = 0; nt < 2; nt++) {
            f16x8 bv = *(const f16x8*)&Bb[fk][nB + nt * 16 + fr][0];
#pragma unroll
            for (int mt = 0; mt < 2; mt++)
                acc[mt][nt] = __builtin_amdgcn_mfma_f32_16x16x32_f16(ah[mt], bv, acc[mt][nt], 0, 0, 0);
        }
    }

#pragma unroll
    for (int mt = 0; mt < 2; mt++) {
#pragma unroll
        for (int nt = 0; nt < 2; nt++) {
            const int d = nB + nt * 16 + fr;
#pragma unroll
            for (int rr = 0; rr < 4; rr++) {
                const int i = i0 + mB + mt * 16 + fk * 4 + rr;
                hout[(b * 512 + i) * 512 + h * 64 + d] = (_Float16)acc[mt][nt][rr];
            }
        }
    }
}

extern "C" void kernel_launch(void* const* d_in, const int* in_sizes, int n_in,
                              void* d_out, int out_size, void* d_ws, size_t ws_size,
                              hipStream_t stream)
{
    const float* x    = (const float*)d_in[0];
    const float* Wq   = (const float*)d_in[1];
    const float* Wk   = (const float*)d_in[2];
    const float* Wv   = (const float*)d_in[3];
    const float* Wo   = (const float*)d_in[4];
    const float* bo   = (const float*)d_in[5];
    const float* gw1  = (const float*)d_in[6];
    const float* gb1  = (const float*)d_in[7];
    const float* gw2  = (const float*)d_in[8];
    const float* gb2  = (const float*)d_in[9];
    const float* gw3  = (const float*)d_in[10];
    const float* gb3  = (const float*)d_in[11];
    const float* cw1  = (const float*)d_in[12];
    const float* cb1  = (const float*)d_in[13];
    const float* cw2  = (const float*)d_in[14];
    const float* cb2  = (const float*)d_in[15];
    const float* alpha = (const float*)d_in[16];
    const float* beta  = (const float*)d_in[17];

    float* out   = (float*)d_out;                 // [2048*512]
    float* attn  = out + 1048576;                 // [32][512][512]
    float* regp  = out + 1048576 + 8388608;
    float* tiout = regp + 1;

    // workspace (~31.2 MB, no aliasing):
    char* ws = (char*)d_ws;
    float*    qkvh1  = (float*)ws;                            // [2048][1664] fp32, 13.63 MB
    unsigned long long* qb = (unsigned long long*)(ws + 13631488);   // 2.62 MB
    unsigned long long* kb = (unsigned long long*)(ws + 16252928);   // 2.62 MB
    _Float16* vmT    = (_Float16*)(ws + 18874368);            // 2 MB
    _Float16* hout_h = (_Float16*)(ws + 20971520);            // 2 MB
    int*      Ti     = (int*)(ws + 23068672);                 // 8 KB
    _Float16* xh     = (_Float16*)(ws + 23076864);            // 2 MB
    _Float16* xl     = (_Float16*)(ws + 25174016);            // 2 MB
    _Float16* WGh    = (_Float16*)(ws + 27271168);            // [1664][512] 1.70 MB
    _Float16* WGl    = (_Float16*)(ws + 28975104);            // 1.70 MB
    _Float16* Woh    = (_Float16*)(ws + 30679040);            // 0.52 MB

    k_convert<<<2112, 256, 0, stream>>>(x, Wq, Wk, Wv, Wo, gw1, cw1,
                                        xh, xl, WGh, WGl, Woh);
    k_gemm3<<<dim3(26, 32), 256, 0, stream>>>(xh, xl, WGh, WGl, qkvh1);
    k_gates2<<<64, 256, 0, stream>>>(qkvh1 + 1536, gb1, cb1, gw2, gb2, gw3, gb3,
                                     cw2, cb2, Ti, tiout);
    k_lif<<<dim3(32, 32), 256, 0, stream>>>(qkvh1, Ti, alpha, beta, qb, kb, vmT);
    k_scores<<<1024, 256, 0, stream>>>(qb, kb, attn, Ti, regp);
    k_av<<<dim3(8, 32), 256, 0, stream>>>(attn, vmT, hout_h);
    k_gemm<512, true><<<dim3(8, 32), 256, 0, stream>>>(hout_h, Woh, bo, out);
}